// Round 9
// baseline (510.061 us; speedup 1.0000x reference)
//
#include <hip/hip_runtime.h>
#include <hip/hip_fp16.h>

#define N_NODES 100000
#define N_EDGES 1600000
#define ELL_W 64
#define ZROW N_NODES               // zero pad row index in XW buffers
#define NCHUNK 128                 // edge chunks
#define NSEG 2                     // node segments
#define CH (N_EDGES / NCHUNK)      // 12500 edges per chunk
#define SEGN (N_NODES / NSEG)      // 50000 nodes per segment
#define MGRID 391                  // mega-kernel grid (<=512 co-resident at 2/CU)
#define NTILES ((N_NODES + 63) / 64)   // 1563

typedef _Float16 half8 __attribute__((ext_vector_type(8)));
typedef float floatx4 __attribute__((ext_vector_type(4)));

// ---------------- Graph build (zero global atomics, u8-packed) — round-7 verbatim ----------------

__global__ __launch_bounds__(512) void k_count(const int* __restrict__ src, const int* __restrict__ dst,
                                               unsigned char* __restrict__ cnt_out,
                                               unsigned char* __restrict__ cnt_in,
                                               int* __restrict__ bar) {
    __shared__ unsigned pkIn[SEGN / 4];      // 50 KB
    __shared__ unsigned pkOut[SEGN / 4];     // 50 KB
    const int c = blockIdx.x;
    const int lo = blockIdx.y * SEGN;
    // zero the mega-kernel's global barrier slots (runs every graph replay)
    if (c == 0 && blockIdx.y == 0 && threadIdx.x < 8)
        __hip_atomic_store(&bar[threadIdx.x], 0, __ATOMIC_RELEASE, __HIP_MEMORY_SCOPE_AGENT);
    for (int i = threadIdx.x; i < SEGN / 4; i += 512) { pkIn[i] = 0; pkOut[i] = 0; }
    __syncthreads();
    const int4* s4 = (const int4*)(src + c * CH);
    const int4* d4 = (const int4*)(dst + c * CH);
    for (int i = threadIdx.x; i < CH / 4; i += 512) {
        int4 s = s4[i], d = d4[i];
        unsigned a;
        a = (unsigned)(s.x - lo); if (a < SEGN) atomicAdd(&pkOut[a >> 2], 1u << ((a & 3) * 8));
        a = (unsigned)(s.y - lo); if (a < SEGN) atomicAdd(&pkOut[a >> 2], 1u << ((a & 3) * 8));
        a = (unsigned)(s.z - lo); if (a < SEGN) atomicAdd(&pkOut[a >> 2], 1u << ((a & 3) * 8));
        a = (unsigned)(s.w - lo); if (a < SEGN) atomicAdd(&pkOut[a >> 2], 1u << ((a & 3) * 8));
        a = (unsigned)(d.x - lo); if (a < SEGN) atomicAdd(&pkIn[a >> 2], 1u << ((a & 3) * 8));
        a = (unsigned)(d.y - lo); if (a < SEGN) atomicAdd(&pkIn[a >> 2], 1u << ((a & 3) * 8));
        a = (unsigned)(d.z - lo); if (a < SEGN) atomicAdd(&pkIn[a >> 2], 1u << ((a & 3) * 8));
        a = (unsigned)(d.w - lo); if (a < SEGN) atomicAdd(&pkIn[a >> 2], 1u << ((a & 3) * 8));
    }
    __syncthreads();
    unsigned* win  = (unsigned*)(cnt_in  + (size_t)c * N_NODES + lo);
    unsigned* wout = (unsigned*)(cnt_out + (size_t)c * N_NODES + lo);
    for (int i = threadIdx.x; i < SEGN / 4; i += 512) { win[i] = pkIn[i]; wout[i] = pkOut[i]; }
}

__global__ __launch_bounds__(256) void k_scan(unsigned char* __restrict__ cnt_in,
                                              const unsigned char* __restrict__ cnt_out,
                                              int* __restrict__ fill, float* __restrict__ norm_src,
                                              float* __restrict__ norm_dst) {
    int d = blockIdx.x * 256 + threadIdx.x;
    if (d >= N_NODES) return;
    int run = 0;
    for (int c = 0; c < NCHUNK; ++c) {
        int v = cnt_in[(size_t)c * N_NODES + d];
        cnt_in[(size_t)c * N_NODES + d] = (unsigned char)run;   // abs slot base fits u8
        run += v;
    }
    int od = 0;
    for (int c = 0; c < NCHUNK; ++c) od += cnt_out[(size_t)c * N_NODES + d];
    fill[d] = run;
    norm_dst[d] = rsqrtf((float)(run < 1 ? 1 : run));
    norm_src[d] = rsqrtf((float)(od  < 1 ? 1 : od ));
}

__global__ __launch_bounds__(512) void k_scatter(const int* __restrict__ src, const int* __restrict__ dst,
                                                 const unsigned char* __restrict__ bases,
                                                 int* __restrict__ ell) {
    __shared__ unsigned base4[SEGN / 4];     // 50 KB
    const int c = blockIdx.x;
    const int lo = blockIdx.y * SEGN;
    const unsigned* bw = (const unsigned*)(bases + (size_t)c * N_NODES + lo);
    for (int i = threadIdx.x; i < SEGN / 4; i += 512) base4[i] = bw[i];
    __syncthreads();
    const int4* s4 = (const int4*)(src + c * CH);
    const int4* d4 = (const int4*)(dst + c * CH);
    for (int i = threadIdx.x; i < CH / 4; i += 512) {
        int4 s = s4[i], d = d4[i];
        unsigned r, sh, old; int p;
        r = (unsigned)(d.x - lo); if (r < SEGN) { sh = (r & 3) * 8; old = atomicAdd(&base4[r >> 2], 1u << sh); p = (old >> sh) & 0xFF; if (p < ELL_W) ell[p * N_NODES + lo + r] = s.x; }
        r = (unsigned)(d.y - lo); if (r < SEGN) { sh = (r & 3) * 8; old = atomicAdd(&base4[r >> 2], 1u << sh); p = (old >> sh) & 0xFF; if (p < ELL_W) ell[p * N_NODES + lo + r] = s.y; }
        r = (unsigned)(d.z - lo); if (r < SEGN) { sh = (r & 3) * 8; old = atomicAdd(&base4[r >> 2], 1u << sh); p = (old >> sh) & 0xFF; if (p < ELL_W) ell[p * N_NODES + lo + r] = s.z; }
        r = (unsigned)(d.w - lo); if (r < SEGN) { sh = (r & 3) * 8; old = atomicAdd(&base4[r >> 2], 1u << sh); p = (old >> sh) & 0xFF; if (p < ELL_W) ell[p * N_NODES + lo + r] = s.w; }
    }
}

// ---------------- accumulate helpers (round-7 verbatim) ----------------
__device__ __forceinline__ void acc16B(const float4& v, float* acc) {
    const __half2* hh = (const __half2*)&v;
    #pragma unroll
    for (int t = 0; t < 4; ++t) {
        float2 f = __half22float2(hh[t]);
        acc[2 * t + 0] += f.x;
        acc[2 * t + 1] += f.y;
    }
}

template<int KK>
__device__ __forceinline__ void loadb8(float4* V, const __half* __restrict__ base,
                                       const int* __restrict__ idxr, int b, int q) {
    #pragma unroll
    for (int u = 0; u < 8; ++u)
        V[u] = *(const float4*)(base + (long)idxr[b + u] * KK + q * 8);
}

__device__ __forceinline__ void accb8(const float4* V, float* acc) {
    #pragma unroll
    for (int u = 0; u < 8; ++u) acc16B(V[u], acc);
}

template<int KK>
__device__ __forceinline__ void gather_row(float* acc, const __half* __restrict__ XW,
                                           const int* __restrict__ idxr, int dg, int q) {
    int nb = (dg + 7) >> 3;
    if (nb <= 0) return;
    float4 va[8], vb[8];
    loadb8<KK>(va, XW, idxr, 0, q);
    int it = 1;
    for (; it + 1 < nb; it += 2) {
        loadb8<KK>(vb, XW, idxr, it * 8, q);
        accb8(va, acc);
        loadb8<KK>(va, XW, idxr, (it + 1) * 8, q);
        accb8(vb, acc);
    }
    if (it < nb) {
        loadb8<KK>(vb, XW, idxr, it * 8, q);
        accb8(va, acc);
        accb8(vb, acc);
    } else {
        accb8(va, acc);
    }
}

// ---------------- software grid barrier (agent scope; per-XCD L2 flush/inv) ----------------
// __syncthreads drains all block stores to L2 (compiler emits vmcnt(0) before
// s_barrier); t0's __threadfence (agent) writes back dirty L2 lines; acquire
// spin + trailing fence invalidates stale L1/L2 before cross-XCD reads.
__device__ __forceinline__ void gbar(int* __restrict__ bar, int idx) {
    __syncthreads();
    if (threadIdx.x == 0) {
        __threadfence();
        atomicAdd(&bar[idx], 1);     // device-scope by default on CDNA
        while (__hip_atomic_load(&bar[idx], __ATOMIC_ACQUIRE, __HIP_MEMORY_SCOPE_AGENT) < MGRID)
            __builtin_amdgcn_s_sleep(8);
        __threadfence();
    }
    __syncthreads();
}

// ---------------- fused agg+GEMM layer as device function ----------------
// smem layout: Xh[64][72] @0 (9216B), Wt[NR][72] @9216 (9216B), sIdx[64][68] @18432
// (17408B), sDeg @35840 (256B), sMax @36096.
template<int NCOL>
__device__ __forceinline__ void agg_layer(char* smem, const __half* __restrict__ XWp,
                                          const int* __restrict__ ell, const int* __restrict__ deg,
                                          const float* __restrict__ norm_dst, const float* __restrict__ biasp,
                                          const float* __restrict__ W, const float* __restrict__ norm,
                                          __half* __restrict__ Y) {
    constexpr int NT = (NCOL + 15) / 16;
    constexpr int NR = NT * 16;
    _Float16 (*Xh)[72] = (_Float16 (*)[72])smem;
    _Float16 (*Wt)[72] = (_Float16 (*)[72])(smem + 9216);
    int (*sIdx)[68]    = (int (*)[68])(smem + 18432);
    int* sDeg          = (int*)(smem + 35840);
    int* sMax          = (int*)(smem + 36096);
    const int tid = threadIdx.x;
    const int lane = tid & 63;
    const int wave = tid >> 6;
    const int quad = lane >> 4;
    const int l16 = lane & 15;

    for (int idx = tid; idx < 64 * NCOL; idx += 512) {
        int k = idx / NCOL, c = idx - (idx / NCOL) * NCOL;
        Wt[c][k] = (_Float16)W[idx];
    }
    for (int idx = tid; idx < (NR - NCOL) * 64; idx += 512) {
        int c = NCOL + idx / 64, k = idx & 63;
        Wt[c][k] = (_Float16)0;
    }

    for (int tt = 0; tt < 4; ++tt) {
        int tile = blockIdx.x * 4 + tt;
        if (tile < NTILES) {
            const int row0 = tile * 64;
            __syncthreads();                    // Wt ready / prev tile LDS free
            if (tid < 64) {
                int node = row0 + tid;
                int dg = 0;
                if (node < N_NODES) { dg = deg[node]; if (dg > ELL_W) dg = ELL_W; }
                sDeg[tid] = dg;
                int v = dg;
                #pragma unroll
                for (int o = 32; o > 0; o >>= 1) v = max(v, __shfl_down(v, o));
                if (tid == 0) *sMax = v;
            }
            __syncthreads();
            const int mpad = (*sMax + 7) & ~7;
            for (int i = tid; i < mpad * 64; i += 512) {
                int slot = i >> 6, r = i & 63;
                int node = row0 + r;
                sIdx[r][slot] = (node < N_NODES && slot < sDeg[r]) ? ell[slot * N_NODES + node] : ZROW;
            }
            __syncthreads();
            {
                int r = tid >> 3, q = tid & 7;
                int d = row0 + r;
                int dg = sDeg[r];
                float acc[8] = {};
                gather_row<64>(acc, XWp, sIdx[r], dg, q);
                _Float16 res[8] = {};
                if (d < N_NODES) {
                    float nd = norm_dst[d];
                    #pragma unroll
                    for (int t = 0; t < 8; ++t) {
                        float o = acc[t] * nd + biasp[q * 8 + t];
                        res[t] = (_Float16)fmaxf(o, 0.f);
                    }
                }
                *(half8*)&Xh[r][q * 8] = *(const half8*)res;
            }
            __syncthreads();
            if (wave < 4) {
                const int r0 = wave * 16;
                floatx4 acc[NT] = {};
                #pragma unroll
                for (int k0 = 0; k0 < 64; k0 += 32) {
                    half8 a = *(const half8*)&Xh[r0 + l16][k0 + quad * 8];
                    #pragma unroll
                    for (int t = 0; t < NT; ++t) {
                        half8 b = *(const half8*)&Wt[t * 16 + l16][k0 + quad * 8];
                        acc[t] = __builtin_amdgcn_mfma_f32_16x16x32_f16(a, b, acc[t], 0, 0, 0);
                    }
                }
                #pragma unroll
                for (int i = 0; i < 4; ++i) {
                    int gr = row0 + r0 + quad * 4 + i;
                    if (gr < N_NODES) {
                        float s = norm[gr];
                        #pragma unroll
                        for (int t = 0; t < NT; ++t) {
                            int c = t * 16 + l16;
                            if (c < NCOL) Y[(long)gr * NCOL + c] = __float2half(acc[t][i] * s);
                        }
                    }
                }
            }
        }
    }
}

// ---------------- MEGA kernel: gemm0 -> bar -> agg1 -> bar -> agg2 -> bar -> aggf ----------------
__global__ __launch_bounds__(512, 4) void k_mega(
        const float* __restrict__ h, const float* __restrict__ W0,
        const float* __restrict__ norm_src, const float* __restrict__ norm_dst,
        const int* __restrict__ ell, const int* __restrict__ deg,
        const float* __restrict__ b0, const float* __restrict__ W1,
        const float* __restrict__ b1, const float* __restrict__ W2,
        const float* __restrict__ b2,
        __half* __restrict__ bufA, __half* __restrict__ bufB, __half* __restrict__ bufC,
        float* __restrict__ out, int* __restrict__ bar) {
    __shared__ __align__(16) char smem[36112];
    const int tid = threadIdx.x;
    const int lane = tid & 63;
    const int wave = tid >> 6;
    const int quad = lane >> 4;
    const int l16 = lane & 15;

    // ---- Phase 0: layer-0 GEMM (fp32 128 -> fp16 64, *norm_src) + pad-row zero ----
    {
        _Float16 (*Xh)[136] = (_Float16 (*)[136])smem;            // 17408 B
        _Float16 (*Wt)[136] = (_Float16 (*)[136])(smem + 17408);  // 17408 B
        if (blockIdx.x == 0) {
            if (tid < 32)      ((unsigned*)(bufA + (size_t)N_NODES * 64))[tid]      = 0u;
            else if (tid < 64) ((unsigned*)(bufB + (size_t)N_NODES * 64))[tid - 32] = 0u;
            else if (tid < 84) ((unsigned*)(bufC + (size_t)N_NODES * 40))[tid - 64] = 0u;
        }
        for (int idx = tid; idx < 128 * 64; idx += 512) {
            int k = idx >> 6, c = idx & 63;
            Wt[c][k] = (_Float16)W0[idx];
        }
        for (int tt = 0; tt < 4; ++tt) {
            int tile = blockIdx.x * 4 + tt;
            if (tile < NTILES) {
                const int row0 = tile * 64;
                __syncthreads();
                for (int idx = tid; idx < 64 * 16; idx += 512) {
                    int r = idx >> 4, kc = idx & 15;
                    int gr = row0 + r;
                    half8 v = {0, 0, 0, 0, 0, 0, 0, 0};
                    if (gr < N_NODES) {
                        const float* X = h + (long)gr * 128 + kc * 8;
                        float4 u0 = *(const float4*)(X + 0);
                        float4 u1 = *(const float4*)(X + 4);
                        v.s0 = (_Float16)u0.x; v.s1 = (_Float16)u0.y;
                        v.s2 = (_Float16)u0.z; v.s3 = (_Float16)u0.w;
                        v.s4 = (_Float16)u1.x; v.s5 = (_Float16)u1.y;
                        v.s6 = (_Float16)u1.z; v.s7 = (_Float16)u1.w;
                    }
                    *(half8*)&Xh[r][kc * 8] = v;
                }
                __syncthreads();
                if (wave < 4) {
                    const int r0 = wave * 16;
                    floatx4 acc[4] = {};
                    #pragma unroll
                    for (int k0 = 0; k0 < 128; k0 += 32) {
                        half8 a = *(const half8*)&Xh[r0 + l16][k0 + quad * 8];
                        #pragma unroll
                        for (int t = 0; t < 4; ++t) {
                            half8 b = *(const half8*)&Wt[t * 16 + l16][k0 + quad * 8];
                            acc[t] = __builtin_amdgcn_mfma_f32_16x16x32_f16(a, b, acc[t], 0, 0, 0);
                        }
                    }
                    #pragma unroll
                    for (int i = 0; i < 4; ++i) {
                        int gr = row0 + r0 + quad * 4 + i;
                        if (gr < N_NODES) {
                            float s = norm_src[gr];
                            #pragma unroll
                            for (int t = 0; t < 4; ++t)
                                bufA[(long)gr * 64 + t * 16 + l16] = __float2half(acc[t][i] * s);
                        }
                    }
                }
            }
        }
    }
    gbar(bar, 0);

    // ---- Phase 1: agg(bufA) -> GEMM W1 -> bufB ----
    agg_layer<64>(smem, bufA, ell, deg, norm_dst, b0, W1, norm_src, bufB);
    gbar(bar, 1);

    // ---- Phase 2: agg(bufB) -> GEMM W2 -> bufC (40-wide) ----
    agg_layer<40>(smem, bufB, ell, deg, norm_dst, b1, W2, norm_src, bufC);
    gbar(bar, 2);

    // ---- Phase 3: final aggregation of bufC -> out (fp32, 40-wide) ----
    {
        int (*sIdx)[68] = (int (*)[68])(smem + 18432);
        int* sDeg       = (int*)(smem + 35840);
        int* sMax       = (int*)(smem + 36096);
        for (int tt = 0; tt < 4; ++tt) {
            int tile = blockIdx.x * 4 + tt;
            if (tile < NTILES) {
                const int row0 = tile * 64;
                __syncthreads();
                if (tid < 64) {
                    int node = row0 + tid;
                    int dg = 0;
                    if (node < N_NODES) { dg = deg[node]; if (dg > ELL_W) dg = ELL_W; }
                    sDeg[tid] = dg;
                    int v = dg;
                    #pragma unroll
                    for (int o = 32; o > 0; o >>= 1) v = max(v, __shfl_down(v, o));
                    if (tid == 0) *sMax = v;
                }
                __syncthreads();
                const int mpad = (*sMax + 7) & ~7;
                for (int i = tid; i < mpad * 64; i += 512) {
                    int slot = i >> 6, r = i & 63;
                    int node = row0 + r;
                    sIdx[r][slot] = (node < N_NODES && slot < sDeg[r]) ? ell[slot * N_NODES + node] : ZROW;
                }
                __syncthreads();
                if (tid < 320) {
                    int r = tid / 5, q = tid - (tid / 5) * 5;
                    int d = row0 + r;
                    if (d < N_NODES) {
                        int dg = sDeg[r];
                        float acc[8] = {};
                        gather_row<40>(acc, bufC, sIdx[r], dg, q);
                        float nd = norm_dst[d];
                        float o[8];
                        #pragma unroll
                        for (int t = 0; t < 8; ++t) o[t] = acc[t] * nd + b2[q * 8 + t];
                        *(float4*)(out + (long)d * 40 + q * 8 + 0) = make_float4(o[0], o[1], o[2], o[3]);
                        *(float4*)(out + (long)d * 40 + q * 8 + 4) = make_float4(o[4], o[5], o[6], o[7]);
                    }
                }
            }
        }
    }
}

extern "C" void kernel_launch(void* const* d_in, const int* in_sizes, int n_in,
                              void* d_out, int out_size, void* d_ws, size_t ws_size,
                              hipStream_t stream) {
    const float* h  = (const float*)d_in[0];
    const float* W0 = (const float*)d_in[1];
    const float* b0 = (const float*)d_in[2];
    const float* W1 = (const float*)d_in[3];
    const float* b1 = (const float*)d_in[4];
    const float* W2 = (const float*)d_in[5];
    const float* b2 = (const float*)d_in[6];
    const int* src  = (const int*)d_in[7];
    const int* dst  = (const int*)d_in[8];
    float* out = (float*)d_out;

    char* ws = (char*)d_ws;
    size_t off = 0;
    int* fill        = (int*)(ws + off); off += (size_t)N_NODES * 4;
    float* norm_src  = (float*)(ws + off); off += (size_t)N_NODES * 4;
    float* norm_dst  = (float*)(ws + off); off += (size_t)N_NODES * 4;
    int* ell         = (int*)(ws + off); off += (size_t)N_NODES * ELL_W * 4;   // [ELL_W][N_NODES] column-major
    // cnt region: cnt_in (12.8 MB) + cnt_out (12.8 MB), dead after k_scatter.
    // bufA (12.8 MB + pad) aliases cnt_in (128 B bleed into cnt_out is fine);
    // bufC (8.0 MB + pad) sits at cnt region + 13.0 MB.
    unsigned char* cnt_in  = (unsigned char*)(ws + off);
    __half* bufA = (__half*)(ws + off);
    __half* bufC = (__half*)(ws + off + 13000000);
    off += (size_t)NCHUNK * N_NODES;                                            // 12.8 MB
    unsigned char* cnt_out = (unsigned char*)(ws + off); off += (size_t)NCHUNK * N_NODES; // 12.8 MB
    __half* bufB  = (__half*)(ws + off); off += (size_t)(N_NODES + 1) * 64 * 2; // 12.8 MB + pad row
    int* bar      = (int*)(ws + off); off += 256;                               // mega barrier slots

    // Build (zero global atomics); k_count also zeroes the barrier slots.
    k_count<<<dim3(NCHUNK, NSEG), 512, 0, stream>>>(src, dst, cnt_out, cnt_in, bar);
    k_scan<<<(N_NODES + 255) / 256, 256, 0, stream>>>(cnt_in, cnt_out, fill, norm_src, norm_dst);
    k_scatter<<<dim3(NCHUNK, NSEG), 512, 0, stream>>>(src, dst, cnt_in, ell);

    // One mega kernel: gemm0 | agg1 | agg2 | aggf with internal grid barriers.
    k_mega<<<MGRID, 512, 0, stream>>>(h, W0, norm_src, norm_dst, ell, fill,
                                      b0, W1, b1, W2, b2, bufA, bufB, bufC, out, bar);
}

// Round 10
// 276.001 us; speedup vs baseline: 1.8480x; 1.8480x over previous
//
#include <hip/hip_runtime.h>
#include <hip/hip_fp16.h>

#define N_NODES 100000
#define N_EDGES 1600000
#define ELL_W 64
#define ZROW N_NODES               // zero pad row index in XW buffers
#define NCHUNK 128                 // edge chunks
#define NSEG 2                     // node segments
#define CH (N_EDGES / NCHUNK)      // 12500 edges per chunk
#define SEGN (N_NODES / NSEG)      // 50000 nodes per segment
#define NTILES ((N_NODES + 63) / 64)   // 1563

typedef _Float16 half8 __attribute__((ext_vector_type(8)));
typedef float floatx4 __attribute__((ext_vector_type(4)));

// ---------------- Graph build (zero global atomics, u8-packed) — round-7 verbatim ----------------

__global__ __launch_bounds__(512) void k_count(const int* __restrict__ src, const int* __restrict__ dst,
                                               unsigned char* __restrict__ cnt_out,
                                               unsigned char* __restrict__ cnt_in) {
    __shared__ unsigned pkIn[SEGN / 4];      // 50 KB
    __shared__ unsigned pkOut[SEGN / 4];     // 50 KB
    const int c = blockIdx.x;
    const int lo = blockIdx.y * SEGN;
    for (int i = threadIdx.x; i < SEGN / 4; i += 512) { pkIn[i] = 0; pkOut[i] = 0; }
    __syncthreads();
    const int4* s4 = (const int4*)(src + c * CH);
    const int4* d4 = (const int4*)(dst + c * CH);
    for (int i = threadIdx.x; i < CH / 4; i += 512) {
        int4 s = s4[i], d = d4[i];
        unsigned a;
        a = (unsigned)(s.x - lo); if (a < SEGN) atomicAdd(&pkOut[a >> 2], 1u << ((a & 3) * 8));
        a = (unsigned)(s.y - lo); if (a < SEGN) atomicAdd(&pkOut[a >> 2], 1u << ((a & 3) * 8));
        a = (unsigned)(s.z - lo); if (a < SEGN) atomicAdd(&pkOut[a >> 2], 1u << ((a & 3) * 8));
        a = (unsigned)(s.w - lo); if (a < SEGN) atomicAdd(&pkOut[a >> 2], 1u << ((a & 3) * 8));
        a = (unsigned)(d.x - lo); if (a < SEGN) atomicAdd(&pkIn[a >> 2], 1u << ((a & 3) * 8));
        a = (unsigned)(d.y - lo); if (a < SEGN) atomicAdd(&pkIn[a >> 2], 1u << ((a & 3) * 8));
        a = (unsigned)(d.z - lo); if (a < SEGN) atomicAdd(&pkIn[a >> 2], 1u << ((a & 3) * 8));
        a = (unsigned)(d.w - lo); if (a < SEGN) atomicAdd(&pkIn[a >> 2], 1u << ((a & 3) * 8));
    }
    __syncthreads();
    unsigned* win  = (unsigned*)(cnt_in  + (size_t)c * N_NODES + lo);
    unsigned* wout = (unsigned*)(cnt_out + (size_t)c * N_NODES + lo);
    for (int i = threadIdx.x; i < SEGN / 4; i += 512) { win[i] = pkIn[i]; wout[i] = pkOut[i]; }
}

__global__ __launch_bounds__(256) void k_scan(unsigned char* __restrict__ cnt_in,
                                              const unsigned char* __restrict__ cnt_out,
                                              int* __restrict__ fill, float* __restrict__ norm_src,
                                              float* __restrict__ norm_dst) {
    int d = blockIdx.x * 256 + threadIdx.x;
    if (d >= N_NODES) return;
    int run = 0;
    for (int c = 0; c < NCHUNK; ++c) {
        int v = cnt_in[(size_t)c * N_NODES + d];
        cnt_in[(size_t)c * N_NODES + d] = (unsigned char)run;   // abs slot base fits u8
        run += v;
    }
    int od = 0;
    for (int c = 0; c < NCHUNK; ++c) od += cnt_out[(size_t)c * N_NODES + d];
    fill[d] = run;
    norm_dst[d] = rsqrtf((float)(run < 1 ? 1 : run));
    norm_src[d] = rsqrtf((float)(od  < 1 ? 1 : od ));
}

// ---------------- Fused scatter || layer-0 GEMM (independent work, one launch) ----------------
// Blocks [0, 256): scatter role — u8-packed slot cursors in LDS, ELL column-major.
// Blocks [256, 256+NTILES): gemm role — one 64-row MFMA tile of bufA = norm.*(h@W0).
// No data overlap: scatter reads cnt_in (bases) + writes ell; gemm reads h/W0/norm_src
// + writes bufA (aliases cnt_out, which is dead after k_scan). Gemm tile 0 also
// zeroes the pad rows of bufA and bufB (bufC's pad is zeroed later by agg1,
// because bufC aliases cnt_in which scatter is still reading here).
__global__ __launch_bounds__(512, 2) void k_scatgemm(const int* __restrict__ src, const int* __restrict__ dst,
                                                     const unsigned char* __restrict__ bases,
                                                     int* __restrict__ ell,
                                                     const float* __restrict__ h, const float* __restrict__ W0,
                                                     const float* __restrict__ norm_src,
                                                     __half* __restrict__ bufA, __half* __restrict__ bufB) {
    __shared__ __align__(16) char smem[50000];
    const int tid = threadIdx.x;

    if (blockIdx.x < NCHUNK * NSEG) {
        // ---- scatter role (round-7 k_scatter verbatim) ----
        unsigned* base4 = (unsigned*)smem;   // SEGN/4 u32 = 50 KB
        const int c = blockIdx.x >> 1;
        const int lo = (blockIdx.x & 1) * SEGN;
        const unsigned* bw = (const unsigned*)(bases + (size_t)c * N_NODES + lo);
        for (int i = tid; i < SEGN / 4; i += 512) base4[i] = bw[i];
        __syncthreads();
        const int4* s4 = (const int4*)(src + c * CH);
        const int4* d4 = (const int4*)(dst + c * CH);
        for (int i = tid; i < CH / 4; i += 512) {
            int4 s = s4[i], d = d4[i];
            unsigned r, sh, old; int p;
            r = (unsigned)(d.x - lo); if (r < SEGN) { sh = (r & 3) * 8; old = atomicAdd(&base4[r >> 2], 1u << sh); p = (old >> sh) & 0xFF; if (p < ELL_W) ell[p * N_NODES + lo + r] = s.x; }
            r = (unsigned)(d.y - lo); if (r < SEGN) { sh = (r & 3) * 8; old = atomicAdd(&base4[r >> 2], 1u << sh); p = (old >> sh) & 0xFF; if (p < ELL_W) ell[p * N_NODES + lo + r] = s.y; }
            r = (unsigned)(d.z - lo); if (r < SEGN) { sh = (r & 3) * 8; old = atomicAdd(&base4[r >> 2], 1u << sh); p = (old >> sh) & 0xFF; if (p < ELL_W) ell[p * N_NODES + lo + r] = s.z; }
            r = (unsigned)(d.w - lo); if (r < SEGN) { sh = (r & 3) * 8; old = atomicAdd(&base4[r >> 2], 1u << sh); p = (old >> sh) & 0xFF; if (p < ELL_W) ell[p * N_NODES + lo + r] = s.w; }
        }
    } else {
        // ---- gemm role: one 64-row tile, K=128, NCOL=64 ----
        _Float16 (*Xh)[136] = (_Float16 (*)[136])smem;            // 17408 B
        _Float16 (*Wt)[136] = (_Float16 (*)[136])(smem + 17408);  // 17408 B
        const int tile = blockIdx.x - NCHUNK * NSEG;
        const int row0 = tile * 64;
        if (tile == 0) {
            if (tid < 32)      ((unsigned*)(bufA + (size_t)N_NODES * 64))[tid]      = 0u;
            else if (tid < 64) ((unsigned*)(bufB + (size_t)N_NODES * 64))[tid - 32] = 0u;
        }
        for (int idx = tid; idx < 128 * 64; idx += 512) {
            int k = idx >> 6, c = idx & 63;
            Wt[c][k] = (_Float16)W0[idx];
        }
        for (int idx = tid; idx < 64 * 16; idx += 512) {
            int r = idx >> 4, kc = idx & 15;
            int gr = row0 + r;
            half8 v = {0, 0, 0, 0, 0, 0, 0, 0};
            if (gr < N_NODES) {
                const float* X = h + (long)gr * 128 + kc * 8;
                float4 u0 = *(const float4*)(X + 0);
                float4 u1 = *(const float4*)(X + 4);
                v.s0 = (_Float16)u0.x; v.s1 = (_Float16)u0.y;
                v.s2 = (_Float16)u0.z; v.s3 = (_Float16)u0.w;
                v.s4 = (_Float16)u1.x; v.s5 = (_Float16)u1.y;
                v.s6 = (_Float16)u1.z; v.s7 = (_Float16)u1.w;
            }
            *(half8*)&Xh[r][kc * 8] = v;
        }
        __syncthreads();
        const int lane = tid & 63;
        const int wave = tid >> 6;
        if (wave < 4) {
            const int quad = lane >> 4;
            const int l16 = lane & 15;
            const int r0 = wave * 16;
            floatx4 acc[4] = {};
            #pragma unroll
            for (int k0 = 0; k0 < 128; k0 += 32) {
                half8 a = *(const half8*)&Xh[r0 + l16][k0 + quad * 8];
                #pragma unroll
                for (int t = 0; t < 4; ++t) {
                    half8 b = *(const half8*)&Wt[t * 16 + l16][k0 + quad * 8];
                    acc[t] = __builtin_amdgcn_mfma_f32_16x16x32_f16(a, b, acc[t], 0, 0, 0);
                }
            }
            #pragma unroll
            for (int i = 0; i < 4; ++i) {
                int gr = row0 + r0 + quad * 4 + i;
                if (gr < N_NODES) {
                    float s = norm_src[gr];
                    #pragma unroll
                    for (int t = 0; t < 4; ++t)
                        bufA[(long)gr * 64 + t * 16 + l16] = __float2half(acc[t][i] * s);
                }
            }
        }
    }
}

// ---------------- accumulate helpers (round-7 verbatim) ----------------
__device__ __forceinline__ void acc16B(const float4& v, float* acc) {
    const __half2* hh = (const __half2*)&v;
    #pragma unroll
    for (int t = 0; t < 4; ++t) {
        float2 f = __half22float2(hh[t]);
        acc[2 * t + 0] += f.x;
        acc[2 * t + 1] += f.y;
    }
}

template<int KK>
__device__ __forceinline__ void loadb8(float4* V, const __half* __restrict__ base,
                                       const int* __restrict__ idxr, int b, int q) {
    #pragma unroll
    for (int u = 0; u < 8; ++u)
        V[u] = *(const float4*)(base + (long)idxr[b + u] * KK + q * 8);
}

__device__ __forceinline__ void accb8(const float4* V, float* acc) {
    #pragma unroll
    for (int u = 0; u < 8; ++u) acc16B(V[u], acc);
}

template<int KK>
__device__ __forceinline__ void gather_row(float* acc, const __half* __restrict__ XW,
                                           const int* __restrict__ idxr, int dg, int q) {
    int nb = (dg + 7) >> 3;
    if (nb <= 0) return;
    float4 va[8], vb[8];
    loadb8<KK>(va, XW, idxr, 0, q);
    int it = 1;
    for (; it + 1 < nb; it += 2) {
        loadb8<KK>(vb, XW, idxr, it * 8, q);
        accb8(va, acc);
        loadb8<KK>(va, XW, idxr, (it + 1) * 8, q);
        accb8(vb, acc);
    }
    if (it < nb) {
        loadb8<KK>(vb, XW, idxr, it * 8, q);
        accb8(va, acc);
        accb8(vb, acc);
    } else {
        accb8(va, acc);
    }
}

// ---------------- Fused agg + GEMM (round-7 verbatim + optional bufC-pad zeroing) ----------------
// __launch_bounds__(512, 4): VGPR cap 128 (pipeline state, no spill).
template<int K, int NCOL>
__global__ __launch_bounds__(512, 4) void k_agg_gemm(const __half* __restrict__ XWp, const int* __restrict__ ell,
                                                     const int* __restrict__ deg, const float* __restrict__ norm_dst,
                                                     const float* __restrict__ biasp, const float* __restrict__ W,
                                                     const float* __restrict__ norm, __half* __restrict__ Y,
                                                     __half* __restrict__ padC) {
    constexpr int NT = (NCOL + 15) / 16;
    constexpr int NR = NT * 16;
    __shared__ __align__(16) _Float16 Xh[64][K + 8];
    __shared__ __align__(16) _Float16 Wt[NR][K + 8];
    __shared__ int sIdx[64][68];
    __shared__ int sDeg[64];
    __shared__ int sMax;
    const int tid = threadIdx.x;
    const int row0 = blockIdx.x * 64;

    // bufC pad-row zero (agg1 only): bufC aliases cnt_in, which is dead only
    // after k_scatgemm — so the earliest safe point is here.
    if (padC && blockIdx.x == 0 && tid < 20)
        ((unsigned*)(padC + (size_t)N_NODES * 40))[tid] = 0u;

    for (int idx = tid; idx < K * NCOL; idx += 512) {
        int k = idx / NCOL, c = idx - (idx / NCOL) * NCOL;
        Wt[c][k] = (_Float16)W[idx];
    }
    for (int idx = tid; idx < (NR - NCOL) * K; idx += 512) {
        int c = NCOL + idx / K, k = idx - (idx / K) * K;
        Wt[c][k] = (_Float16)0;
    }

    if (tid < 64) {
        int node = row0 + tid;
        int dg = 0;
        if (node < N_NODES) { dg = deg[node]; if (dg > ELL_W) dg = ELL_W; }
        sDeg[tid] = dg;
        int v = dg;
        #pragma unroll
        for (int o = 32; o > 0; o >>= 1) v = max(v, __shfl_down(v, o));
        if (tid == 0) sMax = v;
    }
    __syncthreads();
    const int mpad = (sMax + 7) & ~7;        // pad to batch granularity
    for (int i = tid; i < mpad * 64; i += 512) {
        int slot = i >> 6, r = i & 63;
        int node = row0 + r;
        sIdx[r][slot] = (node < N_NODES && slot < sDeg[r]) ? ell[slot * N_NODES + node] : ZROW;
    }
    __syncthreads();

    // Phase 1: pipelined gather into Xh (epilogue: *norm_dst + biasp, ReLU).
    {
        int r = tid >> 3, q = tid & 7;            // K/8 == 8 threads per row
        int d = row0 + r;
        int dg = sDeg[r];
        const int* idxr = sIdx[r];
        float acc[8] = {};
        gather_row<K>(acc, XWp, idxr, dg, q);
        _Float16 res[8] = {};
        if (d < N_NODES) {
            float nd = norm_dst[d];
            #pragma unroll
            for (int t = 0; t < 8; ++t) {
                float o = acc[t] * nd + biasp[q * 8 + t];
                res[t] = (_Float16)fmaxf(o, 0.f);
            }
        }
        *(half8*)&Xh[r][q * 8] = *(const half8*)res;
    }
    __syncthreads();

    const int lane = tid & 63;
    const int wave = tid >> 6;
    if (wave < 4) {
        const int quad = lane >> 4;
        const int l16 = lane & 15;
        const int r0 = wave * 16;

        floatx4 acc[NT] = {};
        #pragma unroll
        for (int k0 = 0; k0 < K; k0 += 32) {
            half8 a = *(const half8*)&Xh[r0 + l16][k0 + quad * 8];
            #pragma unroll
            for (int t = 0; t < NT; ++t) {
                half8 b = *(const half8*)&Wt[t * 16 + l16][k0 + quad * 8];
                acc[t] = __builtin_amdgcn_mfma_f32_16x16x32_f16(a, b, acc[t], 0, 0, 0);
            }
        }

        #pragma unroll
        for (int i = 0; i < 4; ++i) {
            int gr = row0 + r0 + quad * 4 + i;
            if (gr < N_NODES) {
                float s = norm[gr];
                #pragma unroll
                for (int t = 0; t < NT; ++t) {
                    int c = t * 16 + l16;
                    if (c < NCOL) Y[(long)gr * NCOL + c] = __float2half(acc[t][i] * s);
                }
            }
        }
    }
}

// ---------------- Final aggregation (round-7 verbatim) ----------------
template<int NF>
__global__ __launch_bounds__(320, 4) void k_agg_f(const __half* __restrict__ XW, const int* __restrict__ ell,
                                                  const int* __restrict__ deg, const float* __restrict__ norm_dst,
                                                  const float* __restrict__ bias, float* __restrict__ OUT) {
    constexpr int NQ = NF / 8;   // 5
    __shared__ int sIdx[64][68];
    __shared__ int sDeg[64];
    __shared__ int sMax;
    const int tid = threadIdx.x;
    const int row0 = blockIdx.x * 64;

    if (tid < 64) {
        int node = row0 + tid;
        int dg = 0;
        if (node < N_NODES) { dg = deg[node]; if (dg > ELL_W) dg = ELL_W; }
        sDeg[tid] = dg;
        int v = dg;
        #pragma unroll
        for (int o = 32; o > 0; o >>= 1) v = max(v, __shfl_down(v, o));
        if (tid == 0) sMax = v;
    }
    __syncthreads();
    const int mpad = (sMax + 7) & ~7;
    for (int i = tid; i < mpad * 64; i += 320) {
        int slot = i >> 6, r = i & 63;
        int node = row0 + r;
        sIdx[r][slot] = (node < N_NODES && slot < sDeg[r]) ? ell[slot * N_NODES + node] : ZROW;
    }
    __syncthreads();

    const int r = tid / NQ, q = tid - (tid / NQ) * NQ;
    const int d = row0 + r;
    if (d >= N_NODES) return;
    const int dg = sDeg[r];
    const int* idxr = sIdx[r];

    float acc[8] = {};
    gather_row<NF>(acc, XW, idxr, dg, q);

    float nd = norm_dst[d];
    float o[8];
    #pragma unroll
    for (int t = 0; t < 8; ++t) o[t] = acc[t] * nd + bias[q * 8 + t];
    *(float4*)(OUT + (long)d * NF + q * 8 + 0) = make_float4(o[0], o[1], o[2], o[3]);
    *(float4*)(OUT + (long)d * NF + q * 8 + 4) = make_float4(o[4], o[5], o[6], o[7]);
}

extern "C" void kernel_launch(void* const* d_in, const int* in_sizes, int n_in,
                              void* d_out, int out_size, void* d_ws, size_t ws_size,
                              hipStream_t stream) {
    const float* h  = (const float*)d_in[0];
    const float* W0 = (const float*)d_in[1];
    const float* b0 = (const float*)d_in[2];
    const float* W1 = (const float*)d_in[3];
    const float* b1 = (const float*)d_in[4];
    const float* W2 = (const float*)d_in[5];
    const float* b2 = (const float*)d_in[6];
    const int* src  = (const int*)d_in[7];
    const int* dst  = (const int*)d_in[8];
    float* out = (float*)d_out;

    char* ws = (char*)d_ws;
    size_t off = 0;
    int* fill        = (int*)(ws + off); off += (size_t)N_NODES * 4;
    float* norm_src  = (float*)(ws + off); off += (size_t)N_NODES * 4;
    float* norm_dst  = (float*)(ws + off); off += (size_t)N_NODES * 4;
    int* ell         = (int*)(ws + off); off += (size_t)N_NODES * ELL_W * 4;   // [ELL_W][N_NODES] column-major
    // cnt_in (12.8 MB): read by k_scan/k_scatgemm(scatter); bufC (8.0 MB + pad)
    // aliases it — written only from agg2 onward, pad zeroed by agg1.
    unsigned char* cnt_in  = (unsigned char*)(ws + off);
    __half* bufC = (__half*)(ws + off);
    off += (size_t)NCHUNK * N_NODES;                                            // 12.8 MB
    // cnt_out (12.8 MB): dead after k_scan; bufA (12.8 MB + 128 B pad) aliases it.
    unsigned char* cnt_out = (unsigned char*)(ws + off);
    __half* bufA = (__half*)(ws + off);
    off += (size_t)NCHUNK * N_NODES + 256;                                      // 12.8 MB + pad slack
    __half* bufB  = (__half*)(ws + off); off += (size_t)(N_NODES + 1) * 64 * 2; // 12.8 MB + pad row

    // Build:
    k_count<<<dim3(NCHUNK, NSEG), 512, 0, stream>>>(src, dst, cnt_out, cnt_in);
    k_scan<<<(N_NODES + 255) / 256, 256, 0, stream>>>(cnt_in, cnt_out, fill, norm_src, norm_dst);
    // Fused: scatter (blocks 0..255) || layer-0 GEMM (blocks 256..1818)
    k_scatgemm<<<NCHUNK * NSEG + NTILES, 512, 0, stream>>>(src, dst, cnt_in, ell,
                                                           h, W0, norm_src, bufA, bufB);

    const int grid = NTILES;
    // Fused: act1 = relu(agg(XW0)*nd + b0);  bufB = (act1 @ W1) * norm_src  (fp16)
    k_agg_gemm<64, 64><<<grid, 512, 0, stream>>>(bufA, ell, fill, norm_dst, b0, W1, norm_src, bufB, bufC);
    // Fused: act2 = relu(agg(XW1)*nd + b1);  bufC = (act2 @ W2) * norm_src  (fp16, 40-wide)
    k_agg_gemm<64, 40><<<grid, 512, 0, stream>>>(bufB, ell, fill, norm_dst, b1, W2, norm_src, bufC, (__half*)0);
    // Final: out = agg(XW2)*nd + b2  (fp32)
    k_agg_f<40><<<grid, 320, 0, stream>>>(bufC, ell, fill, norm_dst, b2, out);
}